// Round 1
// baseline (24912.938 us; speedup 1.0000x reference)
//
#include <hip/hip_runtime.h>

#define NB   64
#define NSEQ 32
#define NI   31
#define NC   16
#define NH   128
#define NW   256
#define NOUT 10
#define NK   2
#define NSUB (NI*NK)

// Tsit5 tableau (Tsitouras 2011), as in the reference
__device__ const float ATAB[6][5] = {
  {0.f, 0.f, 0.f, 0.f, 0.f},
  {0.161f, 0.f, 0.f, 0.f, 0.f},
  {-0.008480655492356989f, 0.335480655492357f, 0.f, 0.f, 0.f},
  {2.8971530571054935f, -6.359448489975075f, 4.3622954328695815f, 0.f, 0.f},
  {5.325864828439257f, -11.748883564062828f, 7.4955393428898365f, -0.09249506636175525f, 0.f},
  {5.86145544294642f, -12.92096931784711f, 8.159367898576159f, -0.071584973281401f, -0.028269050394068383f}
};
__device__ const float CNODE[6] = {0.f, 0.161f, 0.327f, 0.9f, 0.9800255409045097f, 1.f};
__device__ const float BTAB[6]  = {0.09646076681806523f, 0.01f, 0.4798896504144996f,
                                   1.379008574103742f, -3.290069515436081f, 2.324710524099774f};

__device__ __forceinline__ float softplusf_(float x) {
  // jax.nn.softplus == logaddexp(x, 0) == max(x,0) + log1p(exp(-|x|))
  return fmaxf(x, 0.0f) + log1pf(expf(-fabsf(x)));
}

__global__ __launch_bounds__(256, 1) void ncde_fwd(
    const float* __restrict__ ts,
    const float* __restrict__ cd, const float* __restrict__ cc,
    const float* __restrict__ cb, const float* __restrict__ ca,
    const float* __restrict__ iw0, const float* __restrict__ ib0,
    const float* __restrict__ iw1, const float* __restrict__ ib1,
    const float* __restrict__ iw2, const float* __restrict__ ib2,
    const float* __restrict__ fw0, const float* __restrict__ fb0,
    const float* __restrict__ fw1, const float* __restrict__ fb1,
    const float* __restrict__ fw2, const float* __restrict__ fb2,
    const float* __restrict__ lw,  const float* __restrict__ lb,
    float* __restrict__ out)
{
  const int b = blockIdx.x;
  const int t = threadIdx.x;

  __shared__ float yv[NH];        // state y
  __shared__ float ysv[NH];       // stage state y + h*sum(a*k)
  __shared__ float kv[6][NH];     // k1..k6
  __shared__ float h1s[NW];
  __shared__ float h2s[NW];
  __shared__ float dxs[NC];       // dX/dt at current stage (also reused as x0 in init)
  __shared__ float kpart[256];    // stage-3 partial contractions (also reused for logits)
  __shared__ float tss[NSEQ];
  __shared__ float red[1];

  if (t < NSEQ) tss[t] = ts[t];

  // per-thread cached biases (constant across all 372 f-evals)
  const float fb0t = fb0[t];
  const float fb1t = fb1[t];
  float fb2t[8];
  #pragma unroll
  for (int m = 0; m < 8; ++m) fb2t[m] = fb2[t*8 + m];

  // ---------------- init MLP: y0 = iw2( relu(iw1( relu(iw0 x0) )) ) ----------------
  if (t < NC) dxs[t] = ca[((size_t)b * NI) * NC + t];   // x0 = coeff_a[b, 0, :]
  __syncthreads();
  {
    float a = ib0[t];
    #pragma unroll
    for (int k = 0; k < NC; ++k) a += dxs[k] * iw0[t*NC + k];
    h1s[t] = fmaxf(a, 0.0f);
  }
  __syncthreads();
  {
    const float4* wr = (const float4*)(iw1 + (size_t)t * NW);
    float a0 = 0.f, a1 = 0.f, a2 = 0.f, a3 = 0.f;
    #pragma unroll 8
    for (int k = 0; k < NW/4; ++k) {
      float4 w = wr[k];
      a0 += w.x * h1s[4*k+0]; a1 += w.y * h1s[4*k+1];
      a2 += w.z * h1s[4*k+2]; a3 += w.w * h1s[4*k+3];
    }
    h2s[t] = fmaxf(ib1[t] + ((a0+a1) + (a2+a3)), 0.0f);
  }
  __syncthreads();
  if (t < NH) {
    const float4* wr = (const float4*)(iw2 + (size_t)t * NW);
    float a0 = 0.f, a1 = 0.f, a2 = 0.f, a3 = 0.f;
    #pragma unroll 8
    for (int k = 0; k < NW/4; ++k) {
      float4 w = wr[k];
      a0 += w.x * h2s[4*k+0]; a1 += w.y * h2s[4*k+1];
      a2 += w.z * h2s[4*k+2]; a3 += w.w * h2s[4*k+3];
    }
    yv[t] = ib2[t] + ((a0+a1) + (a2+a3));
  }
  __syncthreads();

  // ---------------- 62 Tsit5 substeps ----------------
  for (int ss = 0; ss < NSUB; ++ss) {
    const int   iv    = ss / NK;
    const int   jv    = ss % NK;
    const float hstep = (tss[iv+1] - tss[iv]) * (1.0f / NK);
    const float t0    = (float)jv * hstep;

    // cache cubic coefficients for this interval (threads 128..143 own channel c)
    float cdv = 0.f, ccv = 0.f, cbv = 0.f;
    if (t >= NH && t < NH + NC) {
      const size_t base = ((size_t)b * NI + iv) * NC + (t - NH);
      cdv = cd[base]; ccv = cc[base]; cbv = cb[base];
    }

    for (int st = 0; st < 6; ++st) {
      // ---- phase A: stage state ysv and control derivative dxs ----
      if (t < NH) {
        float v = yv[t];
        for (int jj = 0; jj < st; ++jj) v += hstep * ATAB[st][jj] * kv[jj][t];
        ysv[t] = v;
      } else if (t < NH + NC) {
        const float frac = t0 + CNODE[st] * hstep;
        dxs[t - NH] = (3.0f * cdv * frac + 2.0f * ccv) * frac + cbv;
      }
      __syncthreads();

      // ---- layer 1: h1 = softplus(fw0 @ ys + fb0), thread t owns output t ----
      {
        const float4* wr = (const float4*)(fw0 + (size_t)t * NH);
        float a0 = 0.f, a1 = 0.f, a2 = 0.f, a3 = 0.f;
        #pragma unroll 8
        for (int k = 0; k < NH/4; ++k) {
          float4 w = wr[k];
          a0 += w.x * ysv[4*k+0]; a1 += w.y * ysv[4*k+1];
          a2 += w.z * ysv[4*k+2]; a3 += w.w * ysv[4*k+3];
        }
        h1s[t] = softplusf_(fb0t + ((a0+a1) + (a2+a3)));
      }
      __syncthreads();

      // ---- layer 2: h2 = softplus(fw1 @ h1 + fb1) ----
      {
        const float4* wr = (const float4*)(fw1 + (size_t)t * NW);
        float a0 = 0.f, a1 = 0.f, a2 = 0.f, a3 = 0.f;
        #pragma unroll 8
        for (int k = 0; k < NW/4; ++k) {
          float4 w = wr[k];
          a0 += w.x * h1s[4*k+0]; a1 += w.y * h1s[4*k+1];
          a2 += w.z * h1s[4*k+2]; a3 += w.w * h1s[4*k+3];
        }
        h2s[t] = softplusf_(fb1t + ((a0+a1) + (a2+a3)));
      }
      __syncthreads();

      // ---- layer 3 + contraction: thread t owns fw2 rows 8t..8t+7 ----
      // row o = 8t+m  ->  h = t>>1,  c = 8*(t&1)+m
      {
        const int c0 = (t & 1) * 8;
        float part = 0.0f;
        #pragma unroll
        for (int m = 0; m < 8; ++m) {
          const float4* wr = (const float4*)(fw2 + ((size_t)(t*8 + m)) * NW);
          float a0 = 0.f, a1 = 0.f, a2 = 0.f, a3 = 0.f;
          #pragma unroll 8
          for (int k = 0; k < NW/4; ++k) {
            float4 w = wr[k];
            a0 += w.x * h2s[4*k+0]; a1 += w.y * h2s[4*k+1];
            a2 += w.z * h2s[4*k+2]; a3 += w.w * h2s[4*k+3];
          }
          part += tanhf(fb2t[m] + ((a0+a1) + (a2+a3))) * dxs[c0 + m];
        }
        kpart[t] = part;
      }
      __syncthreads();
      if (t < NH) kv[st][t] = kpart[2*t] + kpart[2*t+1];
      __syncthreads();
    }

    // ---- y update ----
    if (t < NH) {
      float v = yv[t];
      #pragma unroll
      for (int s2 = 0; s2 < 6; ++s2) v += hstep * BTAB[s2] * kv[s2][t];
      yv[t] = v;
    }
    __syncthreads();
  }

  // ---------------- readout: log_softmax(y @ lw.T + lb) ----------------
  if (t < NOUT) {
    const float4* wr = (const float4*)(lw + (size_t)t * NH);
    float a0 = 0.f, a1 = 0.f, a2 = 0.f, a3 = 0.f;
    #pragma unroll 8
    for (int k = 0; k < NH/4; ++k) {
      float4 w = wr[k];
      a0 += w.x * yv[4*k+0]; a1 += w.y * yv[4*k+1];
      a2 += w.z * yv[4*k+2]; a3 += w.w * yv[4*k+3];
    }
    kpart[t] = lb[t] + ((a0+a1) + (a2+a3));
  }
  __syncthreads();
  if (t == 0) {
    float m = kpart[0];
    for (int o = 1; o < NOUT; ++o) m = fmaxf(m, kpart[o]);
    float se = 0.f;
    for (int o = 0; o < NOUT; ++o) se += expf(kpart[o] - m);
    red[0] = m + logf(se);
  }
  __syncthreads();
  if (t < NOUT) out[b*NOUT + t] = kpart[t] - red[0];
}

extern "C" void kernel_launch(void* const* d_in, const int* in_sizes, int n_in,
                              void* d_out, int out_size, void* d_ws, size_t ws_size,
                              hipStream_t stream) {
  const float* ts  = (const float*)d_in[0];
  const float* cd  = (const float*)d_in[1];
  const float* cc  = (const float*)d_in[2];
  const float* cb  = (const float*)d_in[3];
  const float* ca  = (const float*)d_in[4];
  const float* iw0 = (const float*)d_in[5];
  const float* ib0 = (const float*)d_in[6];
  const float* iw1 = (const float*)d_in[7];
  const float* ib1 = (const float*)d_in[8];
  const float* iw2 = (const float*)d_in[9];
  const float* ib2 = (const float*)d_in[10];
  const float* fw0 = (const float*)d_in[11];
  const float* fb0 = (const float*)d_in[12];
  const float* fw1 = (const float*)d_in[13];
  const float* fb1 = (const float*)d_in[14];
  const float* fw2 = (const float*)d_in[15];
  const float* fb2 = (const float*)d_in[16];
  const float* lw  = (const float*)d_in[17];
  const float* lb  = (const float*)d_in[18];

  ncde_fwd<<<NB, 256, 0, stream>>>(ts, cd, cc, cb, ca, iw0, ib0, iw1, ib1, iw2, ib2,
                                   fw0, fb0, fw1, fb1, fw2, fb2, lw, lb, (float*)d_out);
}

// Round 2
// 24569.958 us; speedup vs baseline: 1.0140x; 1.0140x over previous
//
#include <hip/hip_runtime.h>

#define NB   64
#define NSEQ 32
#define NI   31
#define NC   16
#define NH   128
#define NW   256
#define NOUT 10
#define NK   2
#define NSUB (NI*NK)

// Tsit5 tableau (Tsitouras 2011), as in the reference
__device__ const float ATAB[6][5] = {
  {0.f, 0.f, 0.f, 0.f, 0.f},
  {0.161f, 0.f, 0.f, 0.f, 0.f},
  {-0.008480655492356989f, 0.335480655492357f, 0.f, 0.f, 0.f},
  {2.8971530571054935f, -6.359448489975075f, 4.3622954328695815f, 0.f, 0.f},
  {5.325864828439257f, -11.748883564062828f, 7.4955393428898365f, -0.09249506636175525f, 0.f},
  {5.86145544294642f, -12.92096931784711f, 8.159367898576159f, -0.071584973281401f, -0.028269050394068383f}
};
__device__ const float CNODE[6] = {0.f, 0.161f, 0.327f, 0.9f, 0.9800255409045097f, 1.f};
__device__ const float BTAB[6]  = {0.09646076681806523f, 0.01f, 0.4798896504144996f,
                                   1.379008574103742f, -3.290069515436081f, 2.324710524099774f};

__device__ __forceinline__ float softplusf_(float x) {
  // jax.nn.softplus == logaddexp(x, 0) == max(x,0) + log1p(exp(-|x|))
  return fmaxf(x, 0.0f) + log1pf(expf(-fabsf(x)));
}

__global__ __launch_bounds__(1024, 4) void ncde_fwd(
    const float* __restrict__ ts,
    const float* __restrict__ cd, const float* __restrict__ cc,
    const float* __restrict__ cb, const float* __restrict__ ca,
    const float* __restrict__ iw0, const float* __restrict__ ib0,
    const float* __restrict__ iw1, const float* __restrict__ ib1,
    const float* __restrict__ iw2, const float* __restrict__ ib2,
    const float* __restrict__ fw0, const float* __restrict__ fb0,
    const float* __restrict__ fw1, const float* __restrict__ fb1,
    const float* __restrict__ fw2, const float* __restrict__ fb2,
    const float* __restrict__ lw,  const float* __restrict__ lb,
    float* __restrict__ out)
{
  const int b = blockIdx.x;
  const int t = threadIdx.x;

  __shared__ __align__(16) float yv[NH];       // state y
  __shared__ __align__(16) float ysv[NH];      // stage state
  __shared__ __align__(16) float kv[6][NH];    // k1..k6
  __shared__ __align__(16) float h1s[NW];
  __shared__ __align__(16) float h2s[NW];
  __shared__ __align__(16) float dxs[NC];
  __shared__ float tss[NSEQ];
  __shared__ float lg[NOUT];
  __shared__ float red[1];

  if (t < NSEQ) tss[t] = ts[t];

  // layer1/2 mapping: 4 threads per output row, interleaved float4 K-slices
  const int o4 = t >> 2;          // 0..255
  const int q4 = t & 3;
  // layer3 mapping: thread owns fw2 rows 2t, 2t+1 -> h = t>>3, channels 2*(t&7), +1
  const int h3 = t >> 3;          // 0..127
  const int c0 = 2 * (t & 7);

  const float fb0o = fb0[o4];
  const float fb1o = fb1[o4];
  const float fb2a = fb2[2*t];
  const float fb2b = fb2[2*t + 1];

  // ---------------- init MLP ----------------
  if (t < NC) dxs[t] = ca[((size_t)b * NI) * NC + t];   // x0 = coeff_a[b,0,:]
  __syncthreads();
  if (t < NW) {
    float a = ib0[t];
    #pragma unroll
    for (int k = 0; k < NC; ++k) a += dxs[k] * iw0[t*NC + k];
    h1s[t] = fmaxf(a, 0.0f);
  }
  __syncthreads();
  {
    // i1: 256x256, 4-way K split
    const float4* wr = (const float4*)(iw1 + (size_t)o4 * NW);
    float s = 0.f;
    #pragma unroll
    for (int i = 0; i < 16; ++i) {
      const int j = q4 + 4*i;
      float4 w = wr[j];
      const float4 x = *(const float4*)(h1s + 4*j);
      s += w.x*x.x + w.y*x.y + w.z*x.z + w.w*x.w;
    }
    s += __shfl_xor(s, 1); s += __shfl_xor(s, 2);
    if (q4 == 0) h2s[o4] = fmaxf(ib1[o4] + s, 0.0f);
  }
  __syncthreads();
  {
    // i2: 128x256, 8-way K split
    const int o8 = t >> 3, q8 = t & 7;
    const float4* wr = (const float4*)(iw2 + (size_t)o8 * NW);
    float s = 0.f;
    #pragma unroll
    for (int i = 0; i < 8; ++i) {
      const int j = q8 + 8*i;
      float4 w = wr[j];
      const float4 x = *(const float4*)(h2s + 4*j);
      s += w.x*x.x + w.y*x.y + w.z*x.z + w.w*x.w;
    }
    s += __shfl_xor(s, 1); s += __shfl_xor(s, 2); s += __shfl_xor(s, 4);
    if (q8 == 0) yv[o8] = ib2[o8] + s;
  }
  __syncthreads();

  // ---------------- 62 Tsit5 substeps ----------------
  for (int ss = 0; ss < NSUB; ++ss) {
    const int   iv    = ss / NK;
    const int   jv    = ss % NK;
    const float hstep = (tss[iv+1] - tss[iv]) * (1.0f / NK);
    const float t0    = (float)jv * hstep;

    float cdv = 0.f, ccv = 0.f, cbv = 0.f;
    if (t >= NH && t < NH + NC) {
      const size_t base = ((size_t)b * NI + iv) * NC + (t - NH);
      cdv = cd[base]; ccv = cc[base]; cbv = cb[base];
    }

    for (int st = 0; st < 6; ++st) {
      // ---- phase A: stage state + control derivative ----
      if (t < NH) {
        float v = yv[t];
        for (int jj = 0; jj < st; ++jj) v += hstep * ATAB[st][jj] * kv[jj][t];
        ysv[t] = v;
      } else if (t < NH + NC) {
        const float frac = t0 + CNODE[st] * hstep;
        dxs[t - NH] = (3.0f * cdv * frac + 2.0f * ccv) * frac + cbv;
      }
      __syncthreads();

      // ---- layer 1: h1 = softplus(fw0 @ ys + fb0); 4 threads/output ----
      {
        const float4* wr = (const float4*)(fw0 + (size_t)o4 * NH);
        float s = 0.f;
        #pragma unroll
        for (int i = 0; i < 8; ++i) {
          const int j = q4 + 4*i;
          float4 w = wr[j];
          const float4 x = *(const float4*)(ysv + 4*j);   // lane-uniform -> LDS broadcast
          s += w.x*x.x + w.y*x.y + w.z*x.z + w.w*x.w;
        }
        s += __shfl_xor(s, 1); s += __shfl_xor(s, 2);
        if (q4 == 0) h1s[o4] = softplusf_(fb0o + s);
      }
      __syncthreads();

      // ---- layer 2: h2 = softplus(fw1 @ h1 + fb1); 4 threads/output ----
      {
        const float4* wr = (const float4*)(fw1 + (size_t)o4 * NW);
        float s = 0.f;
        #pragma unroll
        for (int i = 0; i < 16; ++i) {
          const int j = q4 + 4*i;
          float4 w = wr[j];
          const float4 x = *(const float4*)(h1s + 4*j);
          s += w.x*x.x + w.y*x.y + w.z*x.z + w.w*x.w;
        }
        s += __shfl_xor(s, 1); s += __shfl_xor(s, 2);
        if (q4 == 0) h2s[o4] = softplusf_(fb1o + s);
      }
      __syncthreads();

      // ---- layer 3 + contraction: 2 fw2 rows per thread, 8-lane reduce ----
      {
        const float4* wa = (const float4*)(fw2 + ((size_t)(2*t  )) * NW);
        const float4* wb = (const float4*)(fw2 + ((size_t)(2*t+1)) * NW);
        float sa = 0.f, sb = 0.f;
        #pragma unroll 8
        for (int i = 0; i < 64; ++i) {
          const float4 x = *(const float4*)(h2s + 4*i);   // lane-uniform broadcast
          float4 u = wa[i];
          float4 v = wb[i];
          sa += u.x*x.x + u.y*x.y + u.z*x.z + u.w*x.w;
          sb += v.x*x.x + v.y*x.y + v.z*x.z + v.w*x.w;
        }
        float part = tanhf(fb2a + sa) * dxs[c0] + tanhf(fb2b + sb) * dxs[c0 + 1];
        part += __shfl_xor(part, 1);
        part += __shfl_xor(part, 2);
        part += __shfl_xor(part, 4);
        if ((t & 7) == 0) kv[st][h3] = part;
      }
      __syncthreads();
    }

    // ---- y update ----
    if (t < NH) {
      float v = yv[t];
      #pragma unroll
      for (int s2 = 0; s2 < 6; ++s2) v += hstep * BTAB[s2] * kv[s2][t];
      yv[t] = v;
    }
    __syncthreads();
  }

  // ---------------- readout: log_softmax(y @ lw.T + lb) ----------------
  if (t < NOUT) {
    const float4* wr = (const float4*)(lw + (size_t)t * NH);
    float a0 = 0.f;
    #pragma unroll
    for (int k = 0; k < NH/4; ++k) {
      float4 w = wr[k];
      const float4 x = *(const float4*)(yv + 4*k);
      a0 += w.x*x.x + w.y*x.y + w.z*x.z + w.w*x.w;
    }
    lg[t] = lb[t] + a0;
  }
  __syncthreads();
  if (t == 0) {
    float m = lg[0];
    for (int o = 1; o < NOUT; ++o) m = fmaxf(m, lg[o]);
    float se = 0.f;
    for (int o = 0; o < NOUT; ++o) se += expf(lg[o] - m);
    red[0] = m + logf(se);
  }
  __syncthreads();
  if (t < NOUT) out[b*NOUT + t] = lg[t] - red[0];
}

extern "C" void kernel_launch(void* const* d_in, const int* in_sizes, int n_in,
                              void* d_out, int out_size, void* d_ws, size_t ws_size,
                              hipStream_t stream) {
  const float* ts  = (const float*)d_in[0];
  const float* cd  = (const float*)d_in[1];
  const float* cc  = (const float*)d_in[2];
  const float* cb  = (const float*)d_in[3];
  const float* ca  = (const float*)d_in[4];
  const float* iw0 = (const float*)d_in[5];
  const float* ib0 = (const float*)d_in[6];
  const float* iw1 = (const float*)d_in[7];
  const float* ib1 = (const float*)d_in[8];
  const float* iw2 = (const float*)d_in[9];
  const float* ib2 = (const float*)d_in[10];
  const float* fw0 = (const float*)d_in[11];
  const float* fb0 = (const float*)d_in[12];
  const float* fw1 = (const float*)d_in[13];
  const float* fb1 = (const float*)d_in[14];
  const float* fw2 = (const float*)d_in[15];
  const float* fb2 = (const float*)d_in[16];
  const float* lw  = (const float*)d_in[17];
  const float* lb  = (const float*)d_in[18];

  ncde_fwd<<<NB, 1024, 0, stream>>>(ts, cd, cc, cb, ca, iw0, ib0, iw1, ib1, iw2, ib2,
                                    fw0, fb0, fw1, fb1, fw2, fb2, lw, lb, (float*)d_out);
}

// Round 3
// 12591.840 us; speedup vs baseline: 1.9785x; 1.9513x over previous
//
#include <hip/hip_runtime.h>

#define NBATCH 64
#define NSEQ   32
#define NI     31
#define NC     16
#define NH     128
#define NW     256
#define NOUT   10
#define NSUB   62          // 31 intervals * 2 substeps

#define NGRP 8             // batch groups
#define GB   8             // batch rows per group
#define NSL  32            // slice blocks per group
#define NBLK (NGRP*NSL)    // 256 blocks = 1 per CU (LDS-forced)
#define BS   256

// per-slice weight ownership
#define L1R 8              // fw0 rows  (256/32)
#define L2R 8              // fw1 rows  (256/32)
#define L3H 4              // h-dims of fw2 (128/32)
#define L3R 64             // fw2 rows = L3H*16

// padded LDS strides (floats): stride/4 odd -> rows spread across all 8 b128 superbanks
#define P128 132
#define P256 260

// workspace layout (bytes)
#define WS_BAR   0         // 8 groups * 64 ints (cnt at +0, gen at +32 ints)
#define WS_H1    4096      // 64*256 f
#define WS_H2    (4096 + 65536)
#define WS_KV    (4096 + 131072)   // 6*64*128 f = 196608 B

__device__ const float ATAB[6][5] = {
  {0.f, 0.f, 0.f, 0.f, 0.f},
  {0.161f, 0.f, 0.f, 0.f, 0.f},
  {-0.008480655492356989f, 0.335480655492357f, 0.f, 0.f, 0.f},
  {2.8971530571054935f, -6.359448489975075f, 4.3622954328695815f, 0.f, 0.f},
  {5.325864828439257f, -11.748883564062828f, 7.4955393428898365f, -0.09249506636175525f, 0.f},
  {5.86145544294642f, -12.92096931784711f, 8.159367898576159f, -0.071584973281401f, -0.028269050394068383f}
};
__device__ const float CNODE[6] = {0.f, 0.161f, 0.327f, 0.9f, 0.9800255409045097f, 1.f};
__device__ const float BTAB[6]  = {0.09646076681806523f, 0.01f, 0.4798896504144996f,
                                   1.379008574103742f, -3.290069515436081f, 2.324710524099774f};

__device__ __forceinline__ float softplusf_(float x) {
  return fmaxf(x, 0.0f) + log1pf(expf(-fabsf(x)));
}
__device__ __forceinline__ float dot4(float4 a, float4 b) {
  return (a.x*b.x + a.y*b.y) + (a.z*b.z + a.w*b.w);
}

// group barrier: NSL blocks, agent-scope fences make prior global stores visible
__device__ __forceinline__ void group_barrier(int* cnt, int* gen) {
  __syncthreads();
  if (threadIdx.x == 0) {
    __threadfence();   // release: writeback dirty L2 (buffer_wbl2) + drain
    int g = __hip_atomic_load(gen, __ATOMIC_RELAXED, __HIP_MEMORY_SCOPE_AGENT);
    int prev = __hip_atomic_fetch_add(cnt, 1, __ATOMIC_RELAXED, __HIP_MEMORY_SCOPE_AGENT);
    if (prev == NSL - 1) {
      __hip_atomic_store(cnt, 0, __ATOMIC_RELAXED, __HIP_MEMORY_SCOPE_AGENT);
      __hip_atomic_store(gen, g + 1, __ATOMIC_RELEASE, __HIP_MEMORY_SCOPE_AGENT);
    } else {
      while (__hip_atomic_load(gen, __ATOMIC_RELAXED, __HIP_MEMORY_SCOPE_AGENT) == g) {}
    }
    __threadfence();   // acquire: invalidate stale L1/L2 (buffer_inv)
  }
  __syncthreads();
}

__global__ void bar_init(int* bar) {
  if (threadIdx.x < NGRP * 64) bar[threadIdx.x] = 0;
}

__global__ __launch_bounds__(BS) void ncde_fwd(
    const float* __restrict__ ts,
    const float* __restrict__ cd, const float* __restrict__ cc,
    const float* __restrict__ cb, const float* __restrict__ ca,
    const float* __restrict__ iw0, const float* __restrict__ ib0,
    const float* __restrict__ iw1, const float* __restrict__ ib1,
    const float* __restrict__ iw2, const float* __restrict__ ib2,
    const float* __restrict__ fw0, const float* __restrict__ fb0,
    const float* __restrict__ fw1, const float* __restrict__ fb1,
    const float* __restrict__ fw2, const float* __restrict__ fb2,
    const float* __restrict__ lw,  const float* __restrict__ lb,
    int* __restrict__ bar, float* __restrict__ h1g, float* __restrict__ h2g,
    float* __restrict__ kvg, float* __restrict__ out)
{
  const int t  = threadIdx.x;
  const int g  = blockIdx.x & 7;          // group (XCD-locality heuristic; correctness-independent)
  const int s  = blockIdx.x >> 3;         // slice 0..31
  const int gr0 = g * GB;                 // first batch row of group
  int* bcnt = bar + g*64;
  int* bgen = bar + g*64 + 32;

  __shared__ float fw0s[L1R][P128];
  __shared__ float fw1s[L2R][P256];
  __shared__ float fw2s[L3R][P256];
  __shared__ float h1s[GB][P256];
  __shared__ float h2s[GB][P256];
  __shared__ float ysv[GB][P128];
  __shared__ float yloc[GB][NH];
  __shared__ float dxs[GB][NC];
  __shared__ float x0s[GB][NC];
  __shared__ float fb0s[L1R], fb1s[L2R], fb2s[L3R];
  __shared__ float tss[NSEQ];
  __shared__ float lgs[GB][NOUT], lses[GB];

  // ---- one-time: load this slice's weights into LDS ----
  {
    // fw0: 8 rows x 32 f4 -> 1 f4/thread
    int row = t >> 5, j = t & 31;
    *(float4*)&fw0s[row][4*j] = *(const float4*)&fw0[(size_t)(s*L1R + row)*NH + 4*j];
    // fw1: 8 rows x 64 f4 -> 2 f4/thread
    #pragma unroll
    for (int i = 0; i < 2; ++i) {
      int e = t + BS*i; int r2 = e >> 6, j2 = e & 63;
      *(float4*)&fw1s[r2][4*j2] = *(const float4*)&fw1[(size_t)(s*L2R + r2)*NW + 4*j2];
    }
    // fw2: 64 rows x 64 f4 -> 16 f4/thread
    #pragma unroll
    for (int i = 0; i < 16; ++i) {
      int e = t + BS*i; int r2 = e >> 6, j2 = e & 63;
      *(float4*)&fw2s[r2][4*j2] = *(const float4*)&fw2[(size_t)(s*L3R + r2)*NW + 4*j2];
    }
    if (t < L1R) fb0s[t] = fb0[s*L1R + t];
    if (t < L2R) fb1s[t] = fb1[s*L2R + t];
    if (t < L3R) fb2s[t] = fb2[s*L3R + t];
    if (t < NSEQ) tss[t] = ts[t];
  }

  // ---- init MLP (redundant per block, fully local) ----
  if (t < GB*NC) { int r = t >> 4, c = t & 15; x0s[r][c] = ca[((size_t)(gr0 + r)*NI)*NC + c]; }
  __syncthreads();
  #pragma unroll
  for (int i = 0; i < 8; ++i) {           // h1i: 2048 outs
    int e = t + BS*i; int r = e >> 8, row = e & 255;
    float a = ib0[row];
    #pragma unroll
    for (int k = 0; k < NC; ++k) a += iw0[row*NC + k] * x0s[r][k];
    h1s[r][row] = fmaxf(a, 0.f);
  }
  __syncthreads();
  #pragma unroll
  for (int i = 0; i < 8; ++i) {           // h2i
    int e = t + BS*i; int r = e >> 8, row = e & 255;
    float a = ib1[row];
    const float4* wr = (const float4*)&iw1[(size_t)row*NW];
    for (int k = 0; k < 64; ++k) a += dot4(wr[k], *(const float4*)&h1s[r][4*k]);
    h2s[r][row] = fmaxf(a, 0.f);
  }
  __syncthreads();
  #pragma unroll
  for (int i = 0; i < 4; ++i) {           // y0: 1024 outs
    int e = t + BS*i; int r = e >> 7, row = e & 127;
    float a = ib2[row];
    const float4* wr = (const float4*)&iw2[(size_t)row*NW];
    for (int k = 0; k < 64; ++k) a += dot4(wr[k], *(const float4*)&h2s[r][4*k]);
    yloc[r][row] = a;
  }
  __syncthreads();

  // ---- 62 Tsit5 substeps ----
  const int yr = t >> 5, yc4 = 4*(t & 31);    // ys / y-update mapping: one f4 per thread
  const int out6 = t >> 2, q4 = t & 3;        // L1/L2: 4 threads per output
  const int orow = out6 & 7, obat = out6 >> 3;
  const int l3row = t & 63, l3h = l3row >> 4, l3c = l3row & 15, rb = t >> 6; // L3

  for (int ss = 0; ss < NSUB; ++ss) {
    const int iv = ss >> 1, jv = ss & 1;
    const float h = (tss[iv+1] - tss[iv]) * 0.5f;
    const float t0f = (float)jv * h;

    float cdv = 0.f, ccv = 0.f, cbv = 0.f;
    if (t < GB*NC) {
      const size_t base = ((size_t)(gr0 + (t >> 4))*NI + iv)*NC + (t & 15);
      cdv = cd[base]; ccv = cc[base]; cbv = cb[base];
    }

    for (int st = 0; st < 6; ++st) {
      // ---- phase A: stage state (all threads) + dX/dt ----
      {
        float4 v = *(const float4*)&yloc[yr][yc4];
        for (int jj = 0; jj < st; ++jj) {
          const float4 k4 = *(const float4*)&kvg[((size_t)jj*NBATCH + gr0 + yr)*NH + yc4];
          const float a = h * ATAB[st][jj];
          v.x += a*k4.x; v.y += a*k4.y; v.z += a*k4.z; v.w += a*k4.w;
        }
        *(float4*)&ysv[yr][yc4] = v;
        if (t < GB*NC) {
          const float f = t0f + CNODE[st] * h;
          dxs[t >> 4][t & 15] = (3.f*cdv*f + 2.f*ccv)*f + cbv;
        }
      }
      __syncthreads();

      // ---- L1: h1 slice (8 rows x 8 batch, 4 thr/out) ----
      {
        float a = 0.f;
        #pragma unroll
        for (int i = 0; i < 8; ++i) {
          const int j = q4 + 4*i;
          a += dot4(*(const float4*)&fw0s[orow][4*j], *(const float4*)&ysv[obat][4*j]);
        }
        a += __shfl_xor(a, 1); a += __shfl_xor(a, 2);
        if (q4 == 0) h1g[(gr0 + obat)*NW + s*L1R + orow] = softplusf_(fb0s[orow] + a);
      }
      group_barrier(bcnt, bgen);

      // load full h1 (8KB, coalesced)
      #pragma unroll
      for (int i = 0; i < 2; ++i) {
        int e = t + BS*i; int r = e >> 6, j = e & 63;
        *(float4*)&h1s[r][4*j] = *(const float4*)&h1g[(gr0 + r)*NW + 4*j];
      }
      __syncthreads();

      // ---- L2: h2 slice ----
      {
        float a = 0.f;
        #pragma unroll
        for (int i = 0; i < 16; ++i) {
          const int j = q4 + 4*i;
          a += dot4(*(const float4*)&fw1s[orow][4*j], *(const float4*)&h1s[obat][4*j]);
        }
        a += __shfl_xor(a, 1); a += __shfl_xor(a, 2);
        if (q4 == 0) h2g[(gr0 + obat)*NW + s*L2R + orow] = softplusf_(fb1s[orow] + a);
      }
      group_barrier(bcnt, bgen);

      // load full h2
      #pragma unroll
      for (int i = 0; i < 2; ++i) {
        int e = t + BS*i; int r = e >> 6, j = e & 63;
        *(float4*)&h2s[r][4*j] = *(const float4*)&h2g[(gr0 + r)*NW + 4*j];
      }
      __syncthreads();

      // ---- L3: tanh rows + contraction -> kv slice ----
      {
        const int r0 = 2*rb, r1 = 2*rb + 1;
        const float4* wr = (const float4*)&fw2s[l3row][0];
        float a0 = 0.f, a1 = 0.f;
        #pragma unroll 8
        for (int i = 0; i < 64; ++i) {
          const float4 w = wr[i];
          a0 += dot4(w, *(const float4*)&h2s[r0][4*i]);
          a1 += dot4(w, *(const float4*)&h2s[r1][4*i]);
        }
        float v0 = tanhf(a0 + fb2s[l3row]) * dxs[r0][l3c];
        float v1 = tanhf(a1 + fb2s[l3row]) * dxs[r1][l3c];
        v0 += __shfl_xor(v0, 1); v1 += __shfl_xor(v1, 1);
        v0 += __shfl_xor(v0, 2); v1 += __shfl_xor(v1, 2);
        v0 += __shfl_xor(v0, 4); v1 += __shfl_xor(v1, 4);
        v0 += __shfl_xor(v0, 8); v1 += __shfl_xor(v1, 8);
        if (l3c == 0) {
          kvg[((size_t)st*NBATCH + gr0 + r0)*NH + s*L3H + l3h] = v0;
          kvg[((size_t)st*NBATCH + gr0 + r1)*NH + s*L3H + l3h] = v1;
        }
      }
      group_barrier(bcnt, bgen);
    }

    // ---- y update (redundant per block, same mapping as phase A) ----
    {
      float4 v = *(const float4*)&yloc[yr][yc4];
      #pragma unroll
      for (int s2 = 0; s2 < 6; ++s2) {
        const float4 k4 = *(const float4*)&kvg[((size_t)s2*NBATCH + gr0 + yr)*NH + yc4];
        const float a = h * BTAB[s2];
        v.x += a*k4.x; v.y += a*k4.y; v.z += a*k4.z; v.w += a*k4.w;
      }
      *(float4*)&yloc[yr][yc4] = v;
    }
    __syncthreads();
  }

  // ---- readout by slice 0 of each group ----
  if (s == 0) {
    if (t < GB*NOUT) {
      const int r = t / NOUT, o = t % NOUT;
      float a = lb[o];
      const float4* wr = (const float4*)&lw[(size_t)o*NH];
      #pragma unroll
      for (int k = 0; k < 32; ++k) a += dot4(wr[k], *(const float4*)&yloc[r][4*k]);
      lgs[r][o] = a;
    }
    __syncthreads();
    if (t < GB) {
      float m = lgs[t][0];
      for (int o = 1; o < NOUT; ++o) m = fmaxf(m, lgs[t][o]);
      float se = 0.f;
      for (int o = 0; o < NOUT; ++o) se += expf(lgs[t][o] - m);
      lses[t] = m + logf(se);
    }
    __syncthreads();
    if (t < GB*NOUT) {
      const int r = t / NOUT, o = t % NOUT;
      out[(gr0 + r)*NOUT + o] = lgs[r][o] - lses[r];
    }
  }
}

extern "C" void kernel_launch(void* const* d_in, const int* in_sizes, int n_in,
                              void* d_out, int out_size, void* d_ws, size_t ws_size,
                              hipStream_t stream) {
  const float* ts  = (const float*)d_in[0];
  const float* cd  = (const float*)d_in[1];
  const float* cc  = (const float*)d_in[2];
  const float* cb  = (const float*)d_in[3];
  const float* ca  = (const float*)d_in[4];
  const float* iw0 = (const float*)d_in[5];
  const float* ib0 = (const float*)d_in[6];
  const float* iw1 = (const float*)d_in[7];
  const float* ib1 = (const float*)d_in[8];
  const float* iw2 = (const float*)d_in[9];
  const float* ib2 = (const float*)d_in[10];
  const float* fw0 = (const float*)d_in[11];
  const float* fb0 = (const float*)d_in[12];
  const float* fw1 = (const float*)d_in[13];
  const float* fb1 = (const float*)d_in[14];
  const float* fw2 = (const float*)d_in[15];
  const float* fb2 = (const float*)d_in[16];
  const float* lw  = (const float*)d_in[17];
  const float* lb  = (const float*)d_in[18];

  char* ws = (char*)d_ws;
  int*   bar = (int*)(ws + WS_BAR);
  float* h1g = (float*)(ws + WS_H1);
  float* h2g = (float*)(ws + WS_H2);
  float* kvg = (float*)(ws + WS_KV);

  bar_init<<<1, 512, 0, stream>>>(bar);
  ncde_fwd<<<NBLK, BS, 0, stream>>>(ts, cd, cc, cb, ca, iw0, ib0, iw1, ib1, iw2, ib2,
                                    fw0, fb0, fw1, fb1, fw2, fb2, lw, lb,
                                    bar, h1g, h2g, kvg, (float*)d_out);
}

// Round 4
// 4360.836 us; speedup vs baseline: 5.7129x; 2.8875x over previous
//
#include <hip/hip_runtime.h>

#define NBATCH 64
#define NSEQ   32
#define NI     31
#define NC     16
#define NH     128
#define NW     256
#define NOUT   10
#define NSUB   62          // 31 intervals * 2 substeps

#define NGRP 8             // batch groups
#define GB   8             // batch rows per group
#define NSL  32            // slice blocks per group
#define NBLK (NGRP*NSL)    // 256 blocks = 1 per CU (LDS-forced)
#define BS   512

// per-slice weight ownership
#define L1R 8              // fw0 rows  (256/32)
#define L2R 8              // fw1 rows  (256/32)
#define L3H 4              // h-dims of fw2 (128/32)
#define L3R 64             // fw2 rows = L3H*16

// padded LDS strides (floats)
#define P128 132
#define P256 260

// workspace layout (bytes)
#define WS_BAR   0         // 8 groups * 16 u32 counters (monotonic)
#define WS_H1    4096      // 64*256 f
#define WS_H2    (4096 + 65536)
#define WS_KV    (4096 + 131072)   // 6*64*128 f

__device__ const float ATAB[6][5] = {
  {0.f, 0.f, 0.f, 0.f, 0.f},
  {0.161f, 0.f, 0.f, 0.f, 0.f},
  {-0.008480655492356989f, 0.335480655492357f, 0.f, 0.f, 0.f},
  {2.8971530571054935f, -6.359448489975075f, 4.3622954328695815f, 0.f, 0.f},
  {5.325864828439257f, -11.748883564062828f, 7.4955393428898365f, -0.09249506636175525f, 0.f},
  {5.86145544294642f, -12.92096931784711f, 8.159367898576159f, -0.071584973281401f, -0.028269050394068383f}
};
__device__ const float CNODE[6] = {0.f, 0.161f, 0.327f, 0.9f, 0.9800255409045097f, 1.f};
__device__ const float BTAB[6]  = {0.09646076681806523f, 0.01f, 0.4798896504144996f,
                                   1.379008574103742f, -3.290069515436081f, 2.324710524099774f};

__device__ __forceinline__ float softplusf_(float x) {
  return fmaxf(x, 0.0f) + log1pf(expf(-fabsf(x)));
}
__device__ __forceinline__ float dot4(float4 a, float4 b) {
  return (a.x*b.x + a.y*b.y) + (a.z*b.z + a.w*b.w);
}

// cache-bypassing (device-coherent) data transport: sc0 sc1 read/write-through at IF
__device__ __forceinline__ void gstore(float* p, float v) {
  __hip_atomic_store(p, v, __ATOMIC_RELAXED, __HIP_MEMORY_SCOPE_AGENT);
}
__device__ __forceinline__ float gload(const float* p) {
  return __hip_atomic_load(p, __ATOMIC_RELAXED, __HIP_MEMORY_SCOPE_AGENT);
}

// fence-free group barrier: monotonic counter at IF.
// Pre-arrival __syncthreads drains every wave's vmcnt (stores acked at the
// coherence point) before t0 issues the arrival add -> no wbl2/inv needed.
__device__ __forceinline__ void group_barrier(unsigned* cnt, unsigned target) {
  __syncthreads();
  if (threadIdx.x == 0) {
    __hip_atomic_fetch_add(cnt, 1u, __ATOMIC_RELAXED, __HIP_MEMORY_SCOPE_AGENT);
    while (__hip_atomic_load(cnt, __ATOMIC_RELAXED, __HIP_MEMORY_SCOPE_AGENT) < target) {
      __builtin_amdgcn_s_sleep(1);
    }
  }
  __syncthreads();
}

__global__ void bar_init(unsigned* bar) {
  if (threadIdx.x < NGRP * 16) bar[threadIdx.x] = 0u;
}

__global__ __launch_bounds__(BS) void ncde_fwd(
    const float* __restrict__ ts,
    const float* __restrict__ cd, const float* __restrict__ cc,
    const float* __restrict__ cb, const float* __restrict__ ca,
    const float* __restrict__ iw0, const float* __restrict__ ib0,
    const float* __restrict__ iw1, const float* __restrict__ ib1,
    const float* __restrict__ iw2, const float* __restrict__ ib2,
    const float* __restrict__ fw0, const float* __restrict__ fb0,
    const float* __restrict__ fw1, const float* __restrict__ fb1,
    const float* __restrict__ fw2, const float* __restrict__ fb2,
    const float* __restrict__ lw,  const float* __restrict__ lb,
    unsigned* __restrict__ bar, float* __restrict__ h1g, float* __restrict__ h2g,
    float* __restrict__ kvg, float* __restrict__ out)
{
  const int t   = threadIdx.x;
  const int g   = blockIdx.x & 7;         // group (same-XCD heuristic; correctness-independent)
  const int s   = blockIdx.x >> 3;        // slice 0..31
  const int gr0 = g * GB;
  unsigned* bcnt = bar + g * 16;
  unsigned  btarget = 0;

  __shared__ float fw0s[L1R][P128];
  __shared__ float fw1s[L2R][P256];
  __shared__ float fw2s[L3R][P256];
  __shared__ float h1s[GB][P256];
  __shared__ float h2s[GB][P256];
  __shared__ float ysv[GB][P128];
  __shared__ float yloc[GB][NH];
  __shared__ float dxs[GB][NC];
  __shared__ float x0s[GB][NC];
  __shared__ float fb0s[L1R], fb1s[L2R], fb2s[L3R];
  __shared__ float tss[NSEQ];
  __shared__ float lgs[GB][NOUT], lses[GB];

  // ---- one-time: this slice's weights -> LDS (normal cached loads; inputs are read-only) ----
  {
    if (t < 256) {                       // fw0: 8 rows x 32 f4
      int row = t >> 5, j = t & 31;
      *(float4*)&fw0s[row][4*j] = *(const float4*)&fw0[(size_t)(s*L1R + row)*NH + 4*j];
    }
    {                                    // fw1: 8 rows x 64 f4 -> 1 f4/thread
      int r2 = t >> 6, j2 = t & 63;
      *(float4*)&fw1s[r2][4*j2] = *(const float4*)&fw1[(size_t)(s*L2R + r2)*NW + 4*j2];
    }
    #pragma unroll
    for (int i = 0; i < 8; ++i) {        // fw2: 64 rows x 64 f4 -> 8 f4/thread
      int e = t + BS*i; int r2 = e >> 6, j2 = e & 63;
      *(float4*)&fw2s[r2][4*j2] = *(const float4*)&fw2[(size_t)(s*L3R + r2)*NW + 4*j2];
    }
    if (t < L1R) fb0s[t] = fb0[s*L1R + t];
    if (t < L2R) fb1s[t] = fb1[s*L2R + t];
    if (t < L3R) fb2s[t] = fb2[s*L3R + t];
    if (t < NSEQ) tss[t] = ts[t];
  }

  // ---- init MLP (redundant per block, fully local) ----
  if (t < GB*NC) { int r = t >> 4, c = t & 15; x0s[r][c] = ca[((size_t)(gr0 + r)*NI)*NC + c]; }
  __syncthreads();
  #pragma unroll
  for (int i = 0; i < 4; ++i) {          // h1i: 2048 outs
    int e = t + BS*i; int r = e >> 8, row = e & 255;
    float a = ib0[row];
    #pragma unroll
    for (int k = 0; k < NC; ++k) a += iw0[row*NC + k] * x0s[r][k];
    h1s[r][row] = fmaxf(a, 0.f);
  }
  __syncthreads();
  #pragma unroll
  for (int i = 0; i < 4; ++i) {          // h2i
    int e = t + BS*i; int r = e >> 8, row = e & 255;
    float a = ib1[row];
    const float4* wr = (const float4*)&iw1[(size_t)row*NW];
    for (int k = 0; k < 64; ++k) a += dot4(wr[k], *(const float4*)&h1s[r][4*k]);
    h2s[r][row] = fmaxf(a, 0.f);
  }
  __syncthreads();
  #pragma unroll
  for (int i = 0; i < 2; ++i) {          // y0: 1024 outs
    int e = t + BS*i; int r = e >> 7, row = e & 127;
    float a = ib2[row];
    const float4* wr = (const float4*)&iw2[(size_t)row*NW];
    for (int k = 0; k < 64; ++k) a += dot4(wr[k], *(const float4*)&h2s[r][4*k]);
    yloc[r][row] = a;
  }
  __syncthreads();

  // ---- thread mappings for the main loop ----
  const int yr  = t >> 5, yc4 = 4*(t & 31);     // phase A / y-update: t<256 -> one f4
  const int o   = t >> 3, q8 = t & 7;           // L1/L2: 8 threads per output
  const int orow = o & 7, obat = o >> 3;
  const int l3row = t & 63, l3h = l3row >> 4, l3c = l3row & 15, l3b = t >> 6; // L3: 1 row/thread

  // ---- 62 Tsit5 substeps ----
  for (int ss = 0; ss < NSUB; ++ss) {
    const int iv = ss >> 1, jv = ss & 1;
    const float h = (tss[iv+1] - tss[iv]) * 0.5f;
    const float t0f = (float)jv * h;

    float cdv = 0.f, ccv = 0.f, cbv = 0.f;
    if (t >= 256 && t < 256 + GB*NC) {
      const int tc = t - 256;
      const size_t base = ((size_t)(gr0 + (tc >> 4))*NI + iv)*NC + (tc & 15);
      cdv = cd[base]; ccv = cc[base]; cbv = cb[base];
    }

    for (int st = 0; st < 6; ++st) {
      // ---- phase A: stage state (threads 0-255) + dX/dt (threads 256-383) ----
      if (t < 256) {
        float4 v = *(const float4*)&yloc[yr][yc4];
        for (int jj = 0; jj < st; ++jj) {
          const float* kp = &kvg[((size_t)jj*NBATCH + gr0 + yr)*NH + yc4];
          const float a = h * ATAB[st][jj];
          v.x += a*gload(kp+0); v.y += a*gload(kp+1);
          v.z += a*gload(kp+2); v.w += a*gload(kp+3);
        }
        *(float4*)&ysv[yr][yc4] = v;
      } else if (t < 256 + GB*NC) {
        const int tc = t - 256;
        const float f = t0f + CNODE[st] * h;
        dxs[tc >> 4][tc & 15] = (3.f*cdv*f + 2.f*ccv)*f + cbv;
      }
      __syncthreads();

      // ---- L1: h1 slice (8 rows x 8 batch, 8 thr/out) ----
      {
        float a0 = 0.f, a1 = 0.f;
        #pragma unroll
        for (int i = 0; i < 4; i += 2) {
          a0 += dot4(*(const float4*)&fw0s[orow][4*(q8+8*i)],     *(const float4*)&ysv[obat][4*(q8+8*i)]);
          a1 += dot4(*(const float4*)&fw0s[orow][4*(q8+8*(i+1))], *(const float4*)&ysv[obat][4*(q8+8*(i+1))]);
        }
        float a = a0 + a1;
        a += __shfl_xor(a, 1); a += __shfl_xor(a, 2); a += __shfl_xor(a, 4);
        if (q8 == 0) gstore(&h1g[(gr0 + obat)*NW + s*L1R + orow], softplusf_(fb0s[orow] + a));
      }
      group_barrier(bcnt, btarget += NSL);

      // load full h1 (8KB, coalesced bypass loads)
      #pragma unroll
      for (int i = 0; i < 4; ++i) {
        int e = t + BS*i; int r = e >> 8, col = e & 255;
        h1s[r][col] = gload(&h1g[(gr0 + r)*NW + col]);
      }
      __syncthreads();

      // ---- L2: h2 slice ----
      {
        float a0 = 0.f, a1 = 0.f;
        #pragma unroll
        for (int i = 0; i < 8; i += 2) {
          a0 += dot4(*(const float4*)&fw1s[orow][4*(q8+8*i)],     *(const float4*)&h1s[obat][4*(q8+8*i)]);
          a1 += dot4(*(const float4*)&fw1s[orow][4*(q8+8*(i+1))], *(const float4*)&h1s[obat][4*(q8+8*(i+1))]);
        }
        float a = a0 + a1;
        a += __shfl_xor(a, 1); a += __shfl_xor(a, 2); a += __shfl_xor(a, 4);
        if (q8 == 0) gstore(&h2g[(gr0 + obat)*NW + s*L2R + orow], softplusf_(fb1s[orow] + a));
      }
      group_barrier(bcnt, btarget += NSL);

      // load full h2
      #pragma unroll
      for (int i = 0; i < 4; ++i) {
        int e = t + BS*i; int r = e >> 8, col = e & 255;
        h2s[r][col] = gload(&h2g[(gr0 + r)*NW + col]);
      }
      __syncthreads();

      // ---- L3: one fw2 row per thread, 4 accumulators, 16-lane reduce ----
      {
        const float4* wr = (const float4*)&fw2s[l3row][0];
        const float4* xr = (const float4*)&h2s[l3b][0];
        float a0 = 0.f, a1 = 0.f, a2 = 0.f, a3 = 0.f;
        #pragma unroll 4
        for (int i = 0; i < 64; i += 4) {
          a0 += dot4(wr[i+0], xr[i+0]);
          a1 += dot4(wr[i+1], xr[i+1]);
          a2 += dot4(wr[i+2], xr[i+2]);
          a3 += dot4(wr[i+3], xr[i+3]);
        }
        float v0 = tanhf(((a0+a1)+(a2+a3)) + fb2s[l3row]) * dxs[l3b][l3c];
        v0 += __shfl_xor(v0, 1);
        v0 += __shfl_xor(v0, 2);
        v0 += __shfl_xor(v0, 4);
        v0 += __shfl_xor(v0, 8);
        if (l3c == 0) gstore(&kvg[((size_t)st*NBATCH + gr0 + l3b)*NH + s*L3H + l3h], v0);
      }
      group_barrier(bcnt, btarget += NSL);
    }

    // ---- y update (threads 0-255, one f4 each) ----
    if (t < 256) {
      float4 v = *(const float4*)&yloc[yr][yc4];
      #pragma unroll
      for (int s2 = 0; s2 < 6; ++s2) {
        const float* kp = &kvg[((size_t)s2*NBATCH + gr0 + yr)*NH + yc4];
        const float a = h * BTAB[s2];
        v.x += a*gload(kp+0); v.y += a*gload(kp+1);
        v.z += a*gload(kp+2); v.w += a*gload(kp+3);
      }
      *(float4*)&yloc[yr][yc4] = v;
    }
    __syncthreads();
  }

  // ---- readout by slice 0 of each group ----
  if (s == 0) {
    if (t < GB*NOUT) {
      const int r = t / NOUT, oo = t % NOUT;
      float a = lb[oo];
      const float4* wr = (const float4*)&lw[(size_t)oo*NH];
      #pragma unroll
      for (int k = 0; k < 32; ++k) a += dot4(wr[k], *(const float4*)&yloc[r][4*k]);
      lgs[r][oo] = a;
    }
    __syncthreads();
    if (t < GB) {
      float m = lgs[t][0];
      for (int oo = 1; oo < NOUT; ++oo) m = fmaxf(m, lgs[t][oo]);
      float se = 0.f;
      for (int oo = 0; oo < NOUT; ++oo) se += expf(lgs[t][oo] - m);
      lses[t] = m + logf(se);
    }
    __syncthreads();
    if (t < GB*NOUT) {
      const int r = t / NOUT, oo = t % NOUT;
      out[(gr0 + r)*NOUT + oo] = lgs[r][oo] - lses[r];
    }
  }
}

extern "C" void kernel_launch(void* const* d_in, const int* in_sizes, int n_in,
                              void* d_out, int out_size, void* d_ws, size_t ws_size,
                              hipStream_t stream) {
  const float* ts  = (const float*)d_in[0];
  const float* cd  = (const float*)d_in[1];
  const float* cc  = (const float*)d_in[2];
  const float* cb  = (const float*)d_in[3];
  const float* ca  = (const float*)d_in[4];
  const float* iw0 = (const float*)d_in[5];
  const float* ib0 = (const float*)d_in[6];
  const float* iw1 = (const float*)d_in[7];
  const float* ib1 = (const float*)d_in[8];
  const float* iw2 = (const float*)d_in[9];
  const float* ib2 = (const float*)d_in[10];
  const float* fw0 = (const float*)d_in[11];
  const float* fb0 = (const float*)d_in[12];
  const float* fw1 = (const float*)d_in[13];
  const float* fb1 = (const float*)d_in[14];
  const float* fw2 = (const float*)d_in[15];
  const float* fb2 = (const float*)d_in[16];
  const float* lw  = (const float*)d_in[17];
  const float* lb  = (const float*)d_in[18];

  char* ws = (char*)d_ws;
  unsigned* bar = (unsigned*)(ws + WS_BAR);
  float* h1g = (float*)(ws + WS_H1);
  float* h2g = (float*)(ws + WS_H2);
  float* kvg = (float*)(ws + WS_KV);

  bar_init<<<1, 128, 0, stream>>>(bar);
  ncde_fwd<<<NBLK, BS, 0, stream>>>(ts, cd, cc, cb, ca, iw0, ib0, iw1, ib1, iw2, ib2,
                                    fw0, fb0, fw1, fb1, fw2, fb2, lw, lb,
                                    bar, h1g, h2g, kvg, (float*)d_out);
}

// Round 5
// 4135.982 us; speedup vs baseline: 6.0235x; 1.0544x over previous
//
#include <hip/hip_runtime.h>

#define NBATCH 64
#define NSEQ   32
#define NI     31
#define NC     16
#define NH     128
#define NW     256
#define NOUT   10
#define NSUB   62          // 31 intervals * 2 substeps

#define NGRP 8             // batch groups
#define GB   8             // batch rows per group
#define NSL  32            // slice blocks per group
#define NBLK (NGRP*NSL)    // 256 blocks = 1 per CU (LDS-forced)
#define BS   512

// per-slice weight ownership
#define L1R 8              // fw0 rows  (256/32)
#define L2R 8              // fw1 rows  (256/32)
#define L3H 4              // h-dims of fw2 (128/32)
#define L3R 64             // fw2 rows = L3H*16

// padded LDS strides (floats)
#define P128 132
#define P256 260

// workspace layout (bytes)
// barrier slots: 8 groups * 32 slots * 64B = 16 KB
#define WS_BAR   0
#define WS_H1    16384     // 64*256 f
#define WS_H2    (16384 + 65536)
#define WS_KV    (16384 + 131072)   // 6*64*128 f

__device__ const float ATAB[6][5] = {
  {0.f, 0.f, 0.f, 0.f, 0.f},
  {0.161f, 0.f, 0.f, 0.f, 0.f},
  {-0.008480655492356989f, 0.335480655492357f, 0.f, 0.f, 0.f},
  {2.8971530571054935f, -6.359448489975075f, 4.3622954328695815f, 0.f, 0.f},
  {5.325864828439257f, -11.748883564062828f, 7.4955393428898365f, -0.09249506636175525f, 0.f},
  {5.86145544294642f, -12.92096931784711f, 8.159367898576159f, -0.071584973281401f, -0.028269050394068383f}
};
__device__ const float CNODE[6] = {0.f, 0.161f, 0.327f, 0.9f, 0.9800255409045097f, 1.f};
__device__ const float BTAB[6]  = {0.09646076681806523f, 0.01f, 0.4798896504144996f,
                                   1.379008574103742f, -3.290069515436081f, 2.324710524099774f};

__device__ __forceinline__ float softplusf_(float x) {
  return fmaxf(x, 0.0f) + log1pf(expf(-fabsf(x)));
}
__device__ __forceinline__ float dot4(float4 a, float4 b) {
  return (a.x*b.x + a.y*b.y) + (a.z*b.z + a.w*b.w);
}

// device-coherent transport (sc0 sc1: write-through / read-through at the IF)
__device__ __forceinline__ void gstore(float* p, float v) {
  __hip_atomic_store(p, v, __ATOMIC_RELAXED, __HIP_MEMORY_SCOPE_AGENT);
}
__device__ __forceinline__ float gload(const float* p) {
  return __hip_atomic_load(p, __ATOMIC_RELAXED, __HIP_MEMORY_SCOPE_AGENT);
}

// group barrier v2: per-block slots (parallel arrival) + one-wave ballot poll.
// Pre-arrival __syncthreads drains vmcnt (write-through data stores are acked
// at the coherence point before the slot store is issued).
#define SLOT_STRIDE 16     // 16 u32 = 64B per slot
__device__ __forceinline__ void group_barrier(unsigned* slots, int myslot, unsigned seq) {
  __syncthreads();
  if (threadIdx.x == 0) {
    __hip_atomic_store(&slots[myslot * SLOT_STRIDE], seq,
                       __ATOMIC_RELAXED, __HIP_MEMORY_SCOPE_AGENT);
  }
  if (threadIdx.x < 64) {
    const int lane = threadIdx.x & 31;
    for (;;) {
      const unsigned v = __hip_atomic_load(&slots[lane * SLOT_STRIDE],
                                           __ATOMIC_RELAXED, __HIP_MEMORY_SCOPE_AGENT);
      if (__all(v >= seq)) break;
      __builtin_amdgcn_s_sleep(2);
    }
  }
  __syncthreads();
}

__global__ void bar_init(unsigned* bar) {
  const int n = NGRP * NSL * SLOT_STRIDE;   // 4096
  for (int i = threadIdx.x; i < n; i += blockDim.x)
    __hip_atomic_store(&bar[i], 0u, __ATOMIC_RELAXED, __HIP_MEMORY_SCOPE_AGENT);
}

__global__ __launch_bounds__(BS) void ncde_fwd(
    const float* __restrict__ ts,
    const float* __restrict__ cd, const float* __restrict__ cc,
    const float* __restrict__ cb, const float* __restrict__ ca,
    const float* __restrict__ iw0, const float* __restrict__ ib0,
    const float* __restrict__ iw1, const float* __restrict__ ib1,
    const float* __restrict__ iw2, const float* __restrict__ ib2,
    const float* __restrict__ fw0, const float* __restrict__ fb0,
    const float* __restrict__ fw1, const float* __restrict__ fb1,
    const float* __restrict__ fw2, const float* __restrict__ fb2,
    const float* __restrict__ lw,  const float* __restrict__ lb,
    unsigned* __restrict__ bar, float* __restrict__ h1g, float* __restrict__ h2g,
    float* __restrict__ kvg, float* __restrict__ out)
{
  const int t   = threadIdx.x;
  const int g   = blockIdx.x & 7;         // group (same-XCD heuristic; correctness-independent)
  const int s   = blockIdx.x >> 3;        // slice 0..31
  const int gr0 = g * GB;
  unsigned* slots = bar + g * NSL * SLOT_STRIDE;
  unsigned  bseq  = 0;

  __shared__ float fw0s[L1R][P128];
  __shared__ float fw1s[L2R][P256];
  __shared__ float fw2s[L3R][P256];
  __shared__ float h1s[GB][P256];
  __shared__ float h2s[GB][P256];
  __shared__ float ysv[GB][P128];
  __shared__ float yloc[GB][NH];
  __shared__ float dxs[GB][NC];
  __shared__ float x0s[GB][NC];
  __shared__ float fb0s[L1R], fb1s[L2R], fb2s[L3R];
  __shared__ float tss[NSEQ];
  __shared__ float lgs[GB][NOUT], lses[GB];

  // ---- one-time: this slice's weights -> LDS ----
  {
    if (t < 256) {                       // fw0: 8 rows x 32 f4
      int row = t >> 5, j = t & 31;
      *(float4*)&fw0s[row][4*j] = *(const float4*)&fw0[(size_t)(s*L1R + row)*NH + 4*j];
    }
    {                                    // fw1: 8 rows x 64 f4 -> 1 f4/thread
      int r2 = t >> 6, j2 = t & 63;
      *(float4*)&fw1s[r2][4*j2] = *(const float4*)&fw1[(size_t)(s*L2R + r2)*NW + 4*j2];
    }
    #pragma unroll
    for (int i = 0; i < 8; ++i) {        // fw2: 64 rows x 64 f4 -> 8 f4/thread
      int e = t + BS*i; int r2 = e >> 6, j2 = e & 63;
      *(float4*)&fw2s[r2][4*j2] = *(const float4*)&fw2[(size_t)(s*L3R + r2)*NW + 4*j2];
    }
    if (t < L1R) fb0s[t] = fb0[s*L1R + t];
    if (t < L2R) fb1s[t] = fb1[s*L2R + t];
    if (t < L3R) fb2s[t] = fb2[s*L3R + t];
    if (t < NSEQ) tss[t] = ts[t];
  }

  // ---- init MLP (redundant per block, fully local) ----
  if (t < GB*NC) { int r = t >> 4, c = t & 15; x0s[r][c] = ca[((size_t)(gr0 + r)*NI)*NC + c]; }
  __syncthreads();
  #pragma unroll
  for (int i = 0; i < 4; ++i) {          // h1i: 2048 outs
    int e = t + BS*i; int r = e >> 8, row = e & 255;
    float a = ib0[row];
    #pragma unroll
    for (int k = 0; k < NC; ++k) a += iw0[row*NC + k] * x0s[r][k];
    h1s[r][row] = fmaxf(a, 0.f);
  }
  __syncthreads();
  #pragma unroll
  for (int i = 0; i < 4; ++i) {          // h2i
    int e = t + BS*i; int r = e >> 8, row = e & 255;
    float a = ib1[row];
    const float4* wr = (const float4*)&iw1[(size_t)row*NW];
    for (int k = 0; k < 64; ++k) a += dot4(wr[k], *(const float4*)&h1s[r][4*k]);
    h2s[r][row] = fmaxf(a, 0.f);
  }
  __syncthreads();
  #pragma unroll
  for (int i = 0; i < 2; ++i) {          // y0: 1024 outs
    int e = t + BS*i; int r = e >> 7, row = e & 127;
    float a = ib2[row];
    const float4* wr = (const float4*)&iw2[(size_t)row*NW];
    for (int k = 0; k < 64; ++k) a += dot4(wr[k], *(const float4*)&h2s[r][4*k]);
    yloc[r][row] = a;
  }
  __syncthreads();

  // ---- thread mappings ----
  const int yr  = t >> 5, yc4 = 4*(t & 31);     // t<256: one y-f4 (batch yr, cols yc4..+3)
  const int o   = t >> 3, q8 = t & 7;           // L1/L2: 8 threads per output
  const int orow = o & 7, obat = o >> 3;
  const int l3row = t & 63, l3h = l3row >> 4, l3c = l3row & 15, l3b = t >> 6;

  // ---- y and k stages live in registers (t<256) ----
  float4 yreg, kreg[6];
  if (t < 256) yreg = *(const float4*)&yloc[yr][yc4];

  // ---- 62 Tsit5 substeps ----
  for (int ss = 0; ss < NSUB; ++ss) {
    const int iv = ss >> 1, jv = ss & 1;
    const float h = (tss[iv+1] - tss[iv]) * 0.5f;
    const float t0f = (float)jv * h;

    float cdv = 0.f, ccv = 0.f, cbv = 0.f;
    if (t >= 256 && t < 256 + GB*NC) {
      const int tc = t - 256;
      const size_t base = ((size_t)(gr0 + (tc >> 4))*NI + iv)*NC + (tc & 15);
      cdv = cd[base]; ccv = cc[base]; cbv = cb[base];
    }

    for (int st = 0; st < 6; ++st) {
      // ---- phase A: stage state from registers + dX/dt ----
      if (t < 256) {
        float4 v = yreg;
        for (int jj = 0; jj < st; ++jj) {
          const float a = h * ATAB[st][jj];
          v.x += a*kreg[jj].x; v.y += a*kreg[jj].y;
          v.z += a*kreg[jj].z; v.w += a*kreg[jj].w;
        }
        *(float4*)&ysv[yr][yc4] = v;
      } else if (t < 256 + GB*NC) {
        const int tc = t - 256;
        const float f = t0f + CNODE[st] * h;
        dxs[tc >> 4][tc & 15] = (3.f*cdv*f + 2.f*ccv)*f + cbv;
      }
      __syncthreads();

      // ---- L1: h1 slice (8 rows x 8 batch, 8 thr/out) ----
      {
        float a0 = 0.f, a1 = 0.f;
        #pragma unroll
        for (int i = 0; i < 4; i += 2) {
          a0 += dot4(*(const float4*)&fw0s[orow][4*(q8+8*i)],     *(const float4*)&ysv[obat][4*(q8+8*i)]);
          a1 += dot4(*(const float4*)&fw0s[orow][4*(q8+8*(i+1))], *(const float4*)&ysv[obat][4*(q8+8*(i+1))]);
        }
        float a = a0 + a1;
        a += __shfl_xor(a, 1); a += __shfl_xor(a, 2); a += __shfl_xor(a, 4);
        if (q8 == 0) gstore(&h1g[(gr0 + obat)*NW + s*L1R + orow], softplusf_(fb0s[orow] + a));
      }
      group_barrier(slots, s, ++bseq);

      // load full h1 (8KB, coalesced)
      #pragma unroll
      for (int i = 0; i < 4; ++i) {
        int e = t + BS*i; int r = e >> 8, col = e & 255;
        h1s[r][col] = gload(&h1g[(gr0 + r)*NW + col]);
      }
      __syncthreads();

      // ---- L2: h2 slice ----
      {
        float a0 = 0.f, a1 = 0.f;
        #pragma unroll
        for (int i = 0; i < 8; i += 2) {
          a0 += dot4(*(const float4*)&fw1s[orow][4*(q8+8*i)],     *(const float4*)&h1s[obat][4*(q8+8*i)]);
          a1 += dot4(*(const float4*)&fw1s[orow][4*(q8+8*(i+1))], *(const float4*)&h1s[obat][4*(q8+8*(i+1))]);
        }
        float a = a0 + a1;
        a += __shfl_xor(a, 1); a += __shfl_xor(a, 2); a += __shfl_xor(a, 4);
        if (q8 == 0) gstore(&h2g[(gr0 + obat)*NW + s*L2R + orow], softplusf_(fb1s[orow] + a));
      }
      group_barrier(slots, s, ++bseq);

      // load full h2
      #pragma unroll
      for (int i = 0; i < 4; ++i) {
        int e = t + BS*i; int r = e >> 8, col = e & 255;
        h2s[r][col] = gload(&h2g[(gr0 + r)*NW + col]);
      }
      __syncthreads();

      // ---- L3: one fw2 row per thread, 4 accumulators, 16-lane reduce ----
      {
        const float4* wr = (const float4*)&fw2s[l3row][0];
        const float4* xr = (const float4*)&h2s[l3b][0];
        float a0 = 0.f, a1 = 0.f, a2 = 0.f, a3 = 0.f;
        #pragma unroll 4
        for (int i = 0; i < 64; i += 4) {
          a0 += dot4(wr[i+0], xr[i+0]);
          a1 += dot4(wr[i+1], xr[i+1]);
          a2 += dot4(wr[i+2], xr[i+2]);
          a3 += dot4(wr[i+3], xr[i+3]);
        }
        float v0 = tanhf(((a0+a1)+(a2+a3)) + fb2s[l3row]) * dxs[l3b][l3c];
        v0 += __shfl_xor(v0, 1);
        v0 += __shfl_xor(v0, 2);
        v0 += __shfl_xor(v0, 4);
        v0 += __shfl_xor(v0, 8);
        if (l3c == 0) gstore(&kvg[((size_t)st*NBATCH + gr0 + l3b)*NH + s*L3H + l3h], v0);
      }
      group_barrier(slots, s, ++bseq);

      // pull this stage's k into registers (one f4 per t<256 thread)
      if (t < 256) {
        const float* kp = &kvg[((size_t)st*NBATCH + gr0 + yr)*NH + yc4];
        kreg[st].x = gload(kp+0); kreg[st].y = gload(kp+1);
        kreg[st].z = gload(kp+2); kreg[st].w = gload(kp+3);
      }
    }

    // ---- y update in registers ----
    if (t < 256) {
      #pragma unroll
      for (int s2 = 0; s2 < 6; ++s2) {
        const float a = h * BTAB[s2];
        yreg.x += a*kreg[s2].x; yreg.y += a*kreg[s2].y;
        yreg.z += a*kreg[s2].z; yreg.w += a*kreg[s2].w;
      }
    }
  }

  // ---- write y back for readout ----
  if (t < 256) *(float4*)&yloc[yr][yc4] = yreg;
  __syncthreads();

  // ---- readout by slice 0 of each group ----
  if (s == 0) {
    if (t < GB*NOUT) {
      const int r = t / NOUT, oo = t % NOUT;
      float a = lb[oo];
      const float4* wr = (const float4*)&lw[(size_t)oo*NH];
      #pragma unroll
      for (int k = 0; k < 32; ++k) a += dot4(wr[k], *(const float4*)&yloc[r][4*k]);
      lgs[r][oo] = a;
    }
    __syncthreads();
    if (t < GB) {
      float m = lgs[t][0];
      for (int oo = 1; oo < NOUT; ++oo) m = fmaxf(m, lgs[t][oo]);
      float se = 0.f;
      for (int oo = 0; oo < NOUT; ++oo) se += expf(lgs[t][oo] - m);
      lses[t] = m + logf(se);
    }
    __syncthreads();
    if (t < GB*NOUT) {
      const int r = t / NOUT, oo = t % NOUT;
      out[(gr0 + r)*NOUT + oo] = lgs[r][oo] - lses[r];
    }
  }
}

extern "C" void kernel_launch(void* const* d_in, const int* in_sizes, int n_in,
                              void* d_out, int out_size, void* d_ws, size_t ws_size,
                              hipStream_t stream) {
  const float* ts  = (const float*)d_in[0];
  const float* cd  = (const float*)d_in[1];
  const float* cc  = (const float*)d_in[2];
  const float* cb  = (const float*)d_in[3];
  const float* ca  = (const float*)d_in[4];
  const float* iw0 = (const float*)d_in[5];
  const float* ib0 = (const float*)d_in[6];
  const float* iw1 = (const float*)d_in[7];
  const float* ib1 = (const float*)d_in[8];
  const float* iw2 = (const float*)d_in[9];
  const float* ib2 = (const float*)d_in[10];
  const float* fw0 = (const float*)d_in[11];
  const float* fb0 = (const float*)d_in[12];
  const float* fw1 = (const float*)d_in[13];
  const float* fb1 = (const float*)d_in[14];
  const float* fw2 = (const float*)d_in[15];
  const float* fb2 = (const float*)d_in[16];
  const float* lw  = (const float*)d_in[17];
  const float* lb  = (const float*)d_in[18];

  char* ws = (char*)d_ws;
  unsigned* bar = (unsigned*)(ws + WS_BAR);
  float* h1g = (float*)(ws + WS_H1);
  float* h2g = (float*)(ws + WS_H2);
  float* kvg = (float*)(ws + WS_KV);

  bar_init<<<1, 512, 0, stream>>>(bar);
  ncde_fwd<<<NBLK, BS, 0, stream>>>(ts, cd, cc, cb, ca, iw0, ib0, iw1, ib1, iw2, ib2,
                                    fw0, fb0, fw1, fb1, fw2, fb2, lw, lb,
                                    bar, h1g, h2g, kvg, (float*)d_out);
}